// Round 1
// baseline (183.547 us; speedup 1.0000x reference)
//
#include <hip/hip_runtime.h>
#include <math.h>

// GaussianMixture log-likelihood: ll[n] = logsumexp_m( wlog[m] - dx^T G_m dx )
// Strategy: expand the quadratic form into a rank-6 bilinear form
//   arg(n,m) = c0[m] + c1[m]*x0^2 + c2[m]*x0 + c3[m]*x1^2 + c4[m]*x1 + c5[m]*x0*x1
// Coefficients (pre-scaled by log2(e) so exp == native v_exp_f32) are computed
// once per launch by prep_kernel into d_ws (6*M floats = 48 KB).
// Main kernel: 1 sample/thread, loop over M in chunks of 8 with chunked
// online-softmax (one exp per component + one rescale exp per chunk).

#if __has_builtin(__builtin_amdgcn_exp2f)
#define EXP2(x) __builtin_amdgcn_exp2f(x)
#else
#define EXP2(x) exp2f(x)
#endif

__global__ __launch_bounds__(256) void prep_kernel(
    const float* __restrict__ mu,
    const float* __restrict__ A,
    const float* __restrict__ w,
    float* __restrict__ C,   // [6][M]
    int M) {
  __shared__ float red[256];
  const int t = threadIdx.x;

  // log-softmax normalizer over w (M elements)
  float mx = -INFINITY;
  for (int m = t; m < M; m += 256) mx = fmaxf(mx, w[m]);
  red[t] = mx; __syncthreads();
  for (int s = 128; s > 0; s >>= 1) {
    if (t < s) red[t] = fmaxf(red[t], red[t + s]);
    __syncthreads();
  }
  const float wmax = red[0]; __syncthreads();

  float sum = 0.f;
  for (int m = t; m < M; m += 256) sum += expf(w[m] - wmax);
  red[t] = sum; __syncthreads();
  for (int s = 128; s > 0; s >>= 1) {
    if (t < s) red[t] += red[t + s];
    __syncthreads();
  }
  const float logZ = wmax + logf(red[0]);

  const float LOG2E = 1.44269504088896340736f;
  for (int m = t; m < M; m += 256) {
    const float a00 = A[m * 4 + 0], a01 = A[m * 4 + 1];
    const float a10 = A[m * 4 + 2], a11 = A[m * 4 + 3];
    // G = 0.5 * A A^T
    const float g00 = 0.5f * (a00 * a00 + a01 * a01);
    const float g01 = 0.5f * (a00 * a10 + a01 * a11);
    const float g11 = 0.5f * (a10 * a10 + a11 * a11);
    const float g01s = 2.0f * g01;               // g01 + g10
    const float det = g00 * g11 - g01 * g01;
    const float wlog = (w[m] - logZ) + 0.5f * logf(det);
    const float mu0 = mu[m * 2 + 0], mu1 = mu[m * 2 + 1];
    // arg = wlog - [g00*(x0-mu0)^2 + g01s*(x0-mu0)(x1-mu1) + g11*(x1-mu1)^2]
    const float c0 = wlog - (g00 * mu0 * mu0 + g01s * mu0 * mu1 + g11 * mu1 * mu1);
    const float c1 = -g00;
    const float c2 = 2.0f * g00 * mu0 + g01s * mu1;
    const float c3 = -g11;
    const float c4 = 2.0f * g11 * mu1 + g01s * mu0;
    const float c5 = -g01s;
    C[0 * M + m] = LOG2E * c0;
    C[1 * M + m] = LOG2E * c1;
    C[2 * M + m] = LOG2E * c2;
    C[3 * M + m] = LOG2E * c3;
    C[4 * M + m] = LOG2E * c4;
    C[5 * M + m] = LOG2E * c5;
  }
}

__global__ __launch_bounds__(256) void gmix_kernel(
    const float* __restrict__ sample,
    const float* __restrict__ C,
    float* __restrict__ out,
    int N, int M) {
  const int n = blockIdx.x * blockDim.x + threadIdx.x;
  if (n >= N) return;

  const float2 x = ((const float2*)sample)[n];
  const float x0 = x.x, x1 = x.y;
  const float f1 = x0 * x0;   // coeff c1
  const float f3 = x1 * x1;   // coeff c3
  const float f5 = x0 * x1;   // coeff c5

  const float* __restrict__ C0 = C;
  const float* __restrict__ C1 = C + M;
  const float* __restrict__ C2 = C + 2 * M;
  const float* __restrict__ C3 = C + 3 * M;
  const float* __restrict__ C4 = C + 4 * M;
  const float* __restrict__ C5 = C + 5 * M;

  float mx = -INFINITY;
  float s = 0.0f;

  for (int m = 0; m < M; m += 8) {
    float a[8];
#pragma unroll
    for (int j = 0; j < 8; ++j) {
      float t = C1[m + j] * f1;
      t = fmaf(C2[m + j], x0, t);
      t = fmaf(C3[m + j], f3, t);
      t = fmaf(C4[m + j], x1, t);
      t = fmaf(C5[m + j], f5, t);
      a[j] = t + C0[m + j];
    }
    const float cm = fmaxf(fmaxf(fmaxf(a[0], a[1]), fmaxf(a[2], a[3])),
                           fmaxf(fmaxf(a[4], a[5]), fmaxf(a[6], a[7])));
    const float nm = fmaxf(mx, cm);
    s *= EXP2(mx - nm);          // mx=-inf, s=0 on first chunk: 0*0 = 0, safe
    float ls = 0.0f;
#pragma unroll
    for (int j = 0; j < 8; ++j) ls += EXP2(a[j] - nm);
    s += ls;
    mx = nm;
  }

  out[n] = (mx + __log2f(s)) * 0.69314718055994530942f;
}

extern "C" void kernel_launch(void* const* d_in, const int* in_sizes, int n_in,
                              void* d_out, int out_size, void* d_ws, size_t ws_size,
                              hipStream_t stream) {
  const float* sample = (const float*)d_in[0];
  const float* mu     = (const float*)d_in[1];
  const float* A      = (const float*)d_in[2];
  const float* w      = (const float*)d_in[3];
  float* out = (float*)d_out;

  const int N = in_sizes[0] / 2;   // sample is (N,2)
  const int M = in_sizes[3];       // w is (M,1)

  float* C = (float*)d_ws;         // 6*M floats = 48 KB

  prep_kernel<<<1, 256, 0, stream>>>(mu, A, w, C, M);
  gmix_kernel<<<(N + 255) / 256, 256, 0, stream>>>(sample, C, out, N, M);
}

// Round 2
// 145.459 us; speedup vs baseline: 1.2618x; 1.2618x over previous
//
#include <hip/hip_runtime.h>
#include <math.h>

// GaussianMixture log-likelihood: ll[n] = logsumexp_m( wlog[m] - dx^T G_m dx )
// arg(n,m) = c0 + x0*(c1*x0 + c2 + c5*x1) + x1*(c3*x1 + c4)   (5 FMA-class ops)
// Coefficients pre-scaled by log2(e) so exp == native v_exp_f32.
// R2 change: M split 4-ways across blockIdx.y (occupancy 22%->~100%), partial
// logsumexp per split stored in ws, tiny combine kernel merges.

#if __has_builtin(__builtin_amdgcn_exp2f)
#define EXP2(x) __builtin_amdgcn_exp2f(x)
#else
#define EXP2(x) exp2f(x)
#endif

#define SPLIT 4

__global__ __launch_bounds__(256) void prep_kernel(
    const float* __restrict__ mu,
    const float* __restrict__ A,
    const float* __restrict__ w,
    float* __restrict__ C,   // [6][M]
    int M) {
  __shared__ float red[256];
  const int t = threadIdx.x;

  float mx = -INFINITY;
  for (int m = t; m < M; m += 256) mx = fmaxf(mx, w[m]);
  red[t] = mx; __syncthreads();
  for (int s = 128; s > 0; s >>= 1) {
    if (t < s) red[t] = fmaxf(red[t], red[t + s]);
    __syncthreads();
  }
  const float wmax = red[0]; __syncthreads();

  float sum = 0.f;
  for (int m = t; m < M; m += 256) sum += expf(w[m] - wmax);
  red[t] = sum; __syncthreads();
  for (int s = 128; s > 0; s >>= 1) {
    if (t < s) red[t] += red[t + s];
    __syncthreads();
  }
  const float logZ = wmax + logf(red[0]);

  const float LOG2E = 1.44269504088896340736f;
  for (int m = t; m < M; m += 256) {
    const float a00 = A[m * 4 + 0], a01 = A[m * 4 + 1];
    const float a10 = A[m * 4 + 2], a11 = A[m * 4 + 3];
    const float g00 = 0.5f * (a00 * a00 + a01 * a01);
    const float g01 = 0.5f * (a00 * a10 + a01 * a11);
    const float g11 = 0.5f * (a10 * a10 + a11 * a11);
    const float g01s = 2.0f * g01;
    const float det = g00 * g11 - g01 * g01;
    const float wlog = (w[m] - logZ) + 0.5f * logf(det);
    const float mu0 = mu[m * 2 + 0], mu1 = mu[m * 2 + 1];
    const float c0 = wlog - (g00 * mu0 * mu0 + g01s * mu0 * mu1 + g11 * mu1 * mu1);
    const float c1 = -g00;
    const float c2 = 2.0f * g00 * mu0 + g01s * mu1;
    const float c3 = -g11;
    const float c4 = 2.0f * g11 * mu1 + g01s * mu0;
    const float c5 = -g01s;
    C[0 * M + m] = LOG2E * c0;
    C[1 * M + m] = LOG2E * c1;
    C[2 * M + m] = LOG2E * c2;
    C[3 * M + m] = LOG2E * c3;
    C[4 * M + m] = LOG2E * c4;
    C[5 * M + m] = LOG2E * c5;
  }
}

// Each (block.y = split) handles components [split*M/SPLIT, (split+1)*M/SPLIT).
// Writes partial logsumexp (in log2 domain) to P[split*N + n].
__global__ __launch_bounds__(256) void gmix_kernel(
    const float* __restrict__ sample,
    const float* __restrict__ C,
    float* __restrict__ P,
    int N, int M) {
  const int n = blockIdx.x * blockDim.x + threadIdx.x;
  if (n >= N) return;
  const int split = blockIdx.y;
  const int Mq = M / SPLIT;
  const int m0 = split * Mq;

  const float2 x = ((const float2*)sample)[n];
  const float x0 = x.x, x1 = x.y;

  const float* __restrict__ C0 = C + m0;
  const float* __restrict__ C1 = C + M + m0;
  const float* __restrict__ C2 = C + 2 * M + m0;
  const float* __restrict__ C3 = C + 3 * M + m0;
  const float* __restrict__ C4 = C + 4 * M + m0;
  const float* __restrict__ C5 = C + 5 * M + m0;

  float mx = -INFINITY;
  float s = 0.0f;

  for (int m = 0; m < Mq; m += 8) {
    float a[8];
#pragma unroll
    for (int j = 0; j < 8; ++j) {
      // arg = c0 + x0*(c1*x0 + c2 + c5*x1) + x1*(c3*x1 + c4)
      float t0 = fmaf(C1[m + j], x0, C2[m + j]);
      t0 = fmaf(C5[m + j], x1, t0);
      float t1 = fmaf(C3[m + j], x1, C4[m + j]);
      float r = fmaf(t0, x0, C0[m + j]);
      a[j] = fmaf(t1, x1, r);
    }
    const float cm = fmaxf(fmaxf(fmaxf(a[0], a[1]), fmaxf(a[2], a[3])),
                           fmaxf(fmaxf(a[4], a[5]), fmaxf(a[6], a[7])));
    const float nm = fmaxf(mx, cm);
    s *= EXP2(mx - nm);          // first chunk: 0 * exp2(-inf) = 0, safe
    float ls0 = 0.0f, ls1 = 0.0f;
#pragma unroll
    for (int j = 0; j < 8; j += 2) {
      ls0 += EXP2(a[j] - nm);
      ls1 += EXP2(a[j + 1] - nm);
    }
    s += ls0 + ls1;
    mx = nm;
  }

  // partial logsumexp in log2 domain; s >= 1 so finite
  P[split * N + n] = mx + __log2f(s);
}

__global__ __launch_bounds__(256) void combine_kernel(
    const float* __restrict__ P,
    float* __restrict__ out,
    int N) {
  const int n = blockIdx.x * blockDim.x + threadIdx.x;
  if (n >= N) return;
  float p0 = P[0 * N + n];
  float p1 = P[1 * N + n];
  float p2 = P[2 * N + n];
  float p3 = P[3 * N + n];
  float mx = fmaxf(fmaxf(p0, p1), fmaxf(p2, p3));
  float s = EXP2(p0 - mx) + EXP2(p1 - mx) + EXP2(p2 - mx) + EXP2(p3 - mx);
  out[n] = (mx + __log2f(s)) * 0.69314718055994530942f;
}

extern "C" void kernel_launch(void* const* d_in, const int* in_sizes, int n_in,
                              void* d_out, int out_size, void* d_ws, size_t ws_size,
                              hipStream_t stream) {
  const float* sample = (const float*)d_in[0];
  const float* mu     = (const float*)d_in[1];
  const float* A      = (const float*)d_in[2];
  const float* w      = (const float*)d_in[3];
  float* out = (float*)d_out;

  const int N = in_sizes[0] / 2;   // sample is (N,2)
  const int M = in_sizes[3];       // w is (M,1)

  float* C = (float*)d_ws;                       // 6*M floats = 48 KB
  float* P = (float*)d_ws + 6 * M;               // SPLIT*N floats = 2 MB

  prep_kernel<<<1, 256, 0, stream>>>(mu, A, w, C, M);
  dim3 grid((N + 255) / 256, SPLIT);
  gmix_kernel<<<grid, 256, 0, stream>>>(sample, C, P, N, M);
  combine_kernel<<<(N + 255) / 256, 256, 0, stream>>>(P, out, N);
}